// Round 3
// baseline (1783.769 us; speedup 1.0000x reference)
//
#include <hip/hip_runtime.h>

// Problem constants
#define NB 16
#define NH 64
#define NW 64
#define ND 128
#define NK 4096
#define NROWS (NB * NH * NW)        // 65536
#define NSLICE 4
#define SLICE_K (NK / NSLICE)       // 1024
#define OUT_ELEMS (NB * ND * NH * NW)  // 8388608

// ---------------------------------------------------------------------------
// Kernel 1: enorm[k] = ||emb[k]||^2   (one wave per code)
// ---------------------------------------------------------------------------
__global__ void enorm_kernel(const float* __restrict__ emb,
                             float* __restrict__ enorm) {
    int wave = (blockIdx.x * blockDim.x + threadIdx.x) >> 6;
    int lane = threadIdx.x & 63;
    if (wave >= NK) return;
    const float* e = emb + (size_t)wave * ND;
    float a = e[lane];
    float b = e[lane + 64];
    float s = a * a + b * b;
#pragma unroll
    for (int off = 32; off > 0; off >>= 1) s += __shfl_down(s, off, 64);
    if (lane == 0) enorm[wave] = s;
}

// ---------------------------------------------------------------------------
// Kernel 2: argmin. One block per 64-row group. Lane = row, z row in VGPRs
// (loaded DIRECTLY from global: R2 showed an LDS-staged copy gets
// rematerialized as ds_read inside the k-loop — VGPR_Count=76, LDS-bound at
// 385 cyc/k; global loads are not remat'd, forcing register residency).
// Wave = code slice (emb row is wave-uniform -> scalar-load broadcast).
// score_k = ||e_k||^2 - 2 z.e_k  (||z||^2 constant per row, dropped)
// ---------------------------------------------------------------------------
__global__ void __launch_bounds__(256, 2)
argmin_kernel(const float* __restrict__ z,
              const float* __restrict__ emb,
              const float* __restrict__ enorm,
              int* __restrict__ idx_out) {
    __shared__ float red_min[NSLICE * 64];
    __shared__ int red_idx[NSLICE * 64];

    const int bid = blockIdx.x;            // 0..1023 row-group
    const int rowbase = bid * 64;
    const int t = threadIdx.x;
    const int lane = t & 63;
    const int wid = __builtin_amdgcn_readfirstlane(t >> 6);  // wave-uniform slice id

    // This lane's z row, global -> VGPRs. Lane-strided (512B) but successive
    // d reuse the fetched 64B lines via L1/L2; one-time cost ~20us total.
    float4 zr4[32];
    {
        const float4* zrow = (const float4*)(z + (size_t)(rowbase + lane) * ND);
#pragma unroll
        for (int d = 0; d < 32; d++) zr4[d] = zrow[d];
    }

    float best = 3.4e38f;
    int bidx = 0;
    const int k0 = wid * SLICE_K;
    for (int k = k0; k < k0 + SLICE_K; k++) {
        const float4* __restrict__ e4 = (const float4*)(emb + (size_t)k * ND);
        float a0 = 0.f, a1 = 0.f, a2 = 0.f, a3 = 0.f;
#pragma unroll
        for (int d = 0; d < 32; d++) {
            float4 ev = e4[d];             // wave-uniform -> s_load broadcast
            float4 zv = zr4[d];
            a0 = fmaf(zv.x, ev.x, a0);
            a1 = fmaf(zv.y, ev.y, a1);
            a2 = fmaf(zv.z, ev.z, a2);
            a3 = fmaf(zv.w, ev.w, a3);
        }
        float dot = (a0 + a1) + (a2 + a3);
        float s = fmaf(-2.0f, dot, enorm[k]);  // enorm[k]: wave-uniform scalar load
        if (s < best) { best = s; bidx = k; }  // strict < keeps first index
    }

    red_min[wid * 64 + lane] = best;
    red_idx[wid * 64 + lane] = bidx;
    __syncthreads();

    if (wid == 0) {
        float bm = red_min[lane];
        int bi = red_idx[lane];
#pragma unroll
        for (int sl = 1; sl < NSLICE; sl++) {
            float m = red_min[sl * 64 + lane];
            int i2 = red_idx[sl * 64 + lane];
            if (m < bm) { bm = m; bi = i2; }  // ascending slice order => first-idx ties
        }
        idx_out[rowbase + lane] = bi;
    }
}

// ---------------------------------------------------------------------------
// Kernel 3: gather + loss partial + transposed write.
// One block per (b,h): 64 w-positions x 128 d.
// ---------------------------------------------------------------------------
__global__ void out_kernel(const float* __restrict__ z,
                           const float* __restrict__ emb,
                           const int* __restrict__ idx,
                           float* __restrict__ out,
                           float* __restrict__ losspart) {
    __shared__ float zq[64 * 129];
    __shared__ int ids[64];
    __shared__ float redl[4];

    const int bid = blockIdx.x;         // b*64 + h
    const int b = bid >> 6;
    const int h = bid & 63;
    const int rowbase = bid * 64;
    const int t = threadIdx.x;

    if (t < 64) ids[t] = idx[rowbase + t];
    __syncthreads();

    // Pass A: coalesced z reads, emb gather (wave-uniform row), loss accum,
    // fill zq tile in LDS.
    const int d = t & 127;
    const int w0 = t >> 7;
    float lsum = 0.f;
#pragma unroll
    for (int wq = 0; wq < 32; wq++) {
        int w = w0 + 2 * wq;
        float e = emb[(size_t)ids[w] * ND + d];
        float zv = z[((size_t)(rowbase + w)) * ND + d];
        float df = e - zv;
        lsum = fmaf(df, df, lsum);
        zq[w * 129 + d] = e;
    }
#pragma unroll
    for (int off = 32; off > 0; off >>= 1) lsum += __shfl_down(lsum, off, 64);
    if ((t & 63) == 0) redl[t >> 6] = lsum;
    __syncthreads();    // also fences zq writes for pass B
    if (t == 0) losspart[bid] = redl[0] + redl[1] + redl[2] + redl[3];

    // Pass B: out[b][d][h][w], lanes sweep w -> coalesced 256B stores.
    const int w = t & 63;
    const int dq = t >> 6;
#pragma unroll
    for (int dd0 = 0; dd0 < 32; dd0++) {
        int dd = dq + 4 * dd0;
        out[(((size_t)b * ND + dd) * NH + h) * NW + w] = zq[w * 129 + dd];
    }
}

// ---------------------------------------------------------------------------
// Kernel 4: final loss reduce
// ---------------------------------------------------------------------------
__global__ void loss_kernel(const float* __restrict__ losspart,
                            float* __restrict__ out) {
    __shared__ float redl[4];
    const int t = threadIdx.x;
    float s = 0.f;
#pragma unroll
    for (int i = 0; i < 4; i++) s += losspart[t + 256 * i];
#pragma unroll
    for (int off = 32; off > 0; off >>= 1) s += __shfl_down(s, off, 64);
    if ((t & 63) == 0) redl[t >> 6] = s;
    __syncthreads();
    if (t == 0) {
        float total = redl[0] + redl[1] + redl[2] + redl[3];
        out[OUT_ELEMS] = 1.25f * total / (float)OUT_ELEMS;
    }
}

// ---------------------------------------------------------------------------
extern "C" void kernel_launch(void* const* d_in, const int* in_sizes, int n_in,
                              void* d_out, int out_size, void* d_ws, size_t ws_size,
                              hipStream_t stream) {
    const float* z = (const float*)d_in[0];      // [16,64,64,128] fp32
    const float* emb = (const float*)d_in[1];    // [4096,128] fp32
    float* out = (float*)d_out;                  // 8388608 + 1 fp32

    char* ws = (char*)d_ws;
    int* ws_idx = (int*)ws;                          // NROWS ints   (256 KB)
    float* ws_enorm = (float*)(ws + 262144);         // NK floats    (16 KB)
    float* ws_losspart = (float*)(ws + 262144 + 16384);  // 1024 floats

    enorm_kernel<<<NK / 4, 256, 0, stream>>>(emb, ws_enorm);
    argmin_kernel<<<NROWS / 64, 256, 0, stream>>>(z, emb, ws_enorm, ws_idx);
    out_kernel<<<NB * NH, 256, 0, stream>>>(z, emb, ws_idx, out, ws_losspart);
    loss_kernel<<<1, 256, 0, stream>>>(ws_losspart, out);
}